// Round 11
// baseline (753.941 us; speedup 1.0000x reference)
//
#include <hip/hip_runtime.h>
#include <math.h>

#define B_ 4
#define C_ 128
#define H_ 128
#define W_ 128
#define O_ 128
#define HW_ (H_*W_)

typedef __attribute__((ext_vector_type(4))) float f32x4;

// ---------------------------------------------------------------------------
// ws layout (floats):
//   om      f32 [B][27][H][W]        1,769,472
//   featT   f32 [B][H][W][C] NHWC    8,388,608
//   woff_t  f32 [ic256][kk9][oc32]      73,728
//   w_t2    f32 [ckp1152][o128]        147,456   (ckp = k*128 + c)
// total 10,379,264 f = 41.5 MB.  ALL f32 this round — no MFMA anywhere:
// completes the bisection (round-10 showed exact om + simple MFMA main still
// fails at 0.108; this isolates MFMA-fragment-map vs sampling semantics).
// ---------------------------------------------------------------------------

__global__ __launch_bounds__(256)
void transpose_feat(const float* __restrict__ in, float* __restrict__ featT) {
    __shared__ float t[32][33];
    int id = blockIdx.x;
    int ct = id & 3, xt = (id >> 2) & 3, y = (id >> 4) & 127, b = id >> 11;
    int col = threadIdx.x & 31, r0 = threadIdx.x >> 5;
    const float* ip = in + ((size_t)(b * C_) * H_ + y) * W_;
#pragma unroll
    for (int rr = r0; rr < 32; rr += 8)
        t[rr][col] = ip[(ct * 32 + rr) * HW_ + xt * 32 + col];
    __syncthreads();
    float* op = featT + ((size_t)(b * H_ + y) * W_) * C_;
#pragma unroll
    for (int rr = r0; rr < 32; rr += 8)
        op[(xt * 32 + rr) * C_ + ct * 32 + col] = t[col][rr];
}

__global__ void prep_weights(const float* __restrict__ weight,
                             const float* __restrict__ offset_w,
                             float* __restrict__ w_t2,
                             float* __restrict__ woff_t) {
    int i = blockIdx.x * 256 + threadIdx.x;
    if (i < 147456) {
        int ckp = i >> 7, o = i & 127;          // ckp = k*128 + c
        int k_ = ckp >> 7, c = ckp & 127;
        w_t2[i] = weight[o * 1152 + c * 9 + k_];
    }
    int j = i - 147456;
    if (j >= 0 && j < 73728) {
        int ic = j / 288;
        int r  = j - ic * 288;
        int kk = r >> 5, oc = r & 31;
        woff_t[j] = (oc < 27) ? offset_w[(oc * 256 + ic) * 9 + kk] : 0.f;
    }
}

// ---------------------------------------------------------------------------
// Offset conv, exact f32 VALU (audited): om[b][oc27][ho][wo].
// ---------------------------------------------------------------------------
__global__ __launch_bounds__(256, 2)
void offset_conv(const float* __restrict__ input_feat,
                 const float* __restrict__ inter,
                 const float* __restrict__ woff_t,
                 const float* __restrict__ offset_b,
                 float* __restrict__ om) {
    __shared__ __align__(16) float wl[2304];  // 8 ic x 9 kk x 32 oc
    int bid0 = blockIdx.x;
    int r = (bid0 & 7) * 64 + (bid0 >> 3);   // XCD swizzle (512%8==0)
    int b = r >> 7, ho = r & 127;
    int tx = threadIdx.x;
    int p  = tx & 63;
    int og = tx >> 6;

    float acc0[8], acc1[8];
#pragma unroll
    for (int j = 0; j < 8; ++j) {
        int oc = og * 8 + j;
        float bv = (oc < 27) ? offset_b[oc] : 0.f;
        acc0[j] = bv; acc1[j] = bv;
    }
    const float* s0 = input_feat + (size_t)b * C_ * HW_;
    const float* s1 = inter      + (size_t)b * C_ * HW_;

    for (int cc = 0; cc < 32; ++cc) {
        __syncthreads();
        for (int t = tx; t < 2304; t += 256) wl[t] = woff_t[cc * 2304 + t];
        __syncthreads();
#pragma unroll
        for (int icl = 0; icl < 8; ++icl) {
            int ic = cc * 8 + icl;
            const float* src = (ic < 128) ? (s0 + (size_t)ic * HW_)
                                          : (s1 + (size_t)(ic - 128) * HW_);
#pragma unroll
            for (int kh = 0; kh < 3; ++kh) {
                int row = ho - 1 + kh;
                if ((unsigned)row >= 128u) continue;  // block-uniform
                const float* rp = src + row * 128;
                float v0[3], v1[3];
#pragma unroll
                for (int kw = 0; kw < 3; ++kw) {
                    int c0 = p - 1 + kw;
                    v0[kw] = ((unsigned)c0 < 128u) ? rp[c0] : 0.f;
                    int c1 = p + 63 + kw;
                    v1[kw] = (c1 < 128) ? rp[c1] : 0.f;
                }
#pragma unroll
                for (int kw = 0; kw < 3; ++kw) {
                    const float* wp = &wl[(icl * 9 + kh * 3 + kw) * 32 + og * 8];
                    float4 wa = *(const float4*)wp;
                    float4 wb = *(const float4*)(wp + 4);
                    acc0[0] += wa.x * v0[kw]; acc1[0] += wa.x * v1[kw];
                    acc0[1] += wa.y * v0[kw]; acc1[1] += wa.y * v1[kw];
                    acc0[2] += wa.z * v0[kw]; acc1[2] += wa.z * v1[kw];
                    acc0[3] += wa.w * v0[kw]; acc1[3] += wa.w * v1[kw];
                    acc0[4] += wb.x * v0[kw]; acc1[4] += wb.x * v1[kw];
                    acc0[5] += wb.y * v0[kw]; acc1[5] += wb.y * v1[kw];
                    acc0[6] += wb.z * v0[kw]; acc1[6] += wb.z * v1[kw];
                    acc0[7] += wb.w * v0[kw]; acc1[7] += wb.w * v1[kw];
                }
            }
        }
    }
#pragma unroll
    for (int j = 0; j < 8; ++j) {
        int oc = og * 8 + j;
        if (oc < 27) {
            int base = ((b * 27 + oc) * H_ + ho) * W_ + p;
            om[base]      = acc0[j];
            om[base + 64] = acc1[j];
        }
    }
}

// ---------------------------------------------------------------------------
// Main fused sample + ALL-F32 VALU GEMM (bisection round: no MFMA).
// Same fused structure: per (k,cs) stage cols chunk [32ck][64pix] f32 in LDS
// + weights [32ck][128o] f32 in LDS; thread = 8o x 4pix register tile.
// ---------------------------------------------------------------------------
struct BParams { float w00, w01, w10, w11; int b00, b01, b10, b11; };

__device__ __forceinline__ BParams mkParams(int ho, int wo, int k,
                                            float dy, float dx, float mv) {
    float mask = 1.f / (1.f + __expf(-mv));
    int kh = k / 3, kw = k - kh * 3;
    float py = (float)(ho - 1 + kh) + dy;
    float px = (float)(wo - 1 + kw) + dx;
    float y0f = floorf(py), x0f = floorf(px);
    float wy = py - y0f, wx = px - x0f;
    int y0 = (int)y0f, x0 = (int)x0f;
    int y1 = y0 + 1, x1 = x0 + 1;
    float vy0 = ((unsigned)y0 < 128u) ? 1.f : 0.f;
    float vy1 = ((unsigned)y1 < 128u) ? 1.f : 0.f;
    float vx0 = ((unsigned)x0 < 128u) ? 1.f : 0.f;
    float vx1 = ((unsigned)x1 < 128u) ? 1.f : 0.f;
    int yc0 = min(max(y0, 0), 127), yc1 = min(max(y1, 0), 127);
    int xc0 = min(max(x0, 0), 127), xc1 = min(max(x1, 0), 127);
    BParams P;
    P.w00 = (1.f - wy) * (1.f - wx) * mask * vy0 * vx0;
    P.w01 = (1.f - wy) * wx * mask * vy0 * vx1;
    P.w10 = wy * (1.f - wx) * mask * vy1 * vx0;
    P.w11 = wy * wx * mask * vy1 * vx1;
    P.b00 = (yc0 * W_ + xc0) * C_;  P.b01 = (yc0 * W_ + xc1) * C_;
    P.b10 = (yc1 * W_ + xc0) * C_;  P.b11 = (yc1 * W_ + xc1) * C_;
    return P;
}

__global__ __launch_bounds__(256)
void dcn_main_f32(const float* __restrict__ featT, const float* __restrict__ om,
                  const float* __restrict__ w_t2,
                  const float* __restrict__ bias, float* __restrict__ out) {
    __shared__ __align__(16) float colsF[32][72];
    __shared__ __align__(16) float wlf[32][132];

    int bid0 = blockIdx.x;
    int bid = (bid0 & 7) * 128 + (bid0 >> 3);    // XCD swizzle (1024%8==0)
    int wt = bid & 1, ho = (bid >> 1) & 127, b = bid >> 8;
    int wo0 = wt * 64;
    int tx = threadIdx.x;
    int pix = tx & 63, cg = tx >> 6;             // staging role
    int o8 = (tx >> 4) << 3, p4 = (tx & 15) << 2; // GEMM role
    int wo = wo0 + pix;

    f32x4 acc[8];
#pragma unroll
    for (int j = 0; j < 8; ++j) acc[j] = (f32x4)(0.f);

    const float* fb  = featT + (size_t)b * HW_ * C_;
    const float* omb = om + (size_t)b * 27 * HW_ + ho * W_ + wo;

    f32x4 L[8];
    f32x4 sA, sB;
    auto LDC = [&](const BParams& Q, int cs) {
        int cb = cs * 32 + cg * 8;
        const float* p00 = fb + Q.b00 + cb;
        const float* p01 = fb + Q.b01 + cb;
        const float* p10 = fb + Q.b10 + cb;
        const float* p11 = fb + Q.b11 + cb;
        L[0] = *(const f32x4*)p00; L[4] = *(const f32x4*)(p00 + 4);
        L[1] = *(const f32x4*)p01; L[5] = *(const f32x4*)(p01 + 4);
        L[2] = *(const f32x4*)p10; L[6] = *(const f32x4*)(p10 + 4);
        L[3] = *(const f32x4*)p11; L[7] = *(const f32x4*)(p11 + 4);
    };
    auto CMB = [&](const BParams& Q) {
        sA = Q.w00 * L[0] + Q.w01 * L[1] + Q.w10 * L[2] + Q.w11 * L[3];
        sB = Q.w00 * L[4] + Q.w01 * L[5] + Q.w10 * L[6] + Q.w11 * L[7];
    };

    for (int k = 0; k < 9; ++k) {
        float dy = omb[(2 * k) * HW_];
        float dx = omb[(2 * k + 1) * HW_];
        float mv = omb[(18 + k) * HW_];
        BParams P = mkParams(ho, wo, k, dy, dx, mv);
        LDC(P, 0);
#pragma unroll
        for (int cs = 0; cs < 4; ++cs) {
            int s = k * 4 + cs;
            CMB(P);                        // combine chunk cs from L
            __syncthreads();               // prior step's LDS reads complete
            // stage cols chunk: rows = channel-within-chunk, cols = pixel
            colsF[cg * 8 + 0][pix] = sA[0];
            colsF[cg * 8 + 1][pix] = sA[1];
            colsF[cg * 8 + 2][pix] = sA[2];
            colsF[cg * 8 + 3][pix] = sA[3];
            colsF[cg * 8 + 4][pix] = sB[0];
            colsF[cg * 8 + 5][pix] = sB[1];
            colsF[cg * 8 + 6][pix] = sB[2];
            colsF[cg * 8 + 7][pix] = sB[3];
            // stage weights for step s: wlf[kk][o] = w_t2[s*32+kk][o]
#pragma unroll
            for (int pp = 0; pp < 4; ++pp) {
                int idx = pp * 256 + tx;
                int kk = idx >> 5, og4 = idx & 31;
                *(f32x4*)&wlf[kk][og4 * 4] =
                    *(const f32x4*)&w_t2[(size_t)(s * 32 + kk) * 128 + og4 * 4];
            }
            if (cs < 3) LDC(P, cs + 1);    // next chunk loads overlap GEMM
            __syncthreads();               // staging visible

            // GEMM: 32 K x (8o x 4pix) per thread
#pragma unroll 4
            for (int ck = 0; ck < 32; ++ck) {
                f32x4 cv = *(const f32x4*)&colsF[ck][p4];
                f32x4 wa = *(const f32x4*)&wlf[ck][o8];
                f32x4 wb = *(const f32x4*)&wlf[ck][o8 + 4];
                acc[0] += wa.x * cv;  acc[1] += wa.y * cv;
                acc[2] += wa.z * cv;  acc[3] += wa.w * cv;
                acc[4] += wb.x * cv;  acc[5] += wb.y * cv;
                acc[6] += wb.z * cv;  acc[7] += wb.w * cv;
            }
        }
    }

    // epilogue: thread owns o8..o8+7 x pixels wo0+p4..+3
#pragma unroll
    for (int j = 0; j < 8; ++j) {
        float bv = bias[o8 + j];
        f32x4 rv = acc[j] + (f32x4)(bv);
        *(f32x4*)(out + (((size_t)b * O_ + o8 + j) * H_ + ho) * W_ + wo0 + p4) = rv;
    }
}

extern "C" void kernel_launch(void* const* d_in, const int* in_sizes, int n_in,
                              void* d_out, int out_size, void* d_ws, size_t ws_size,
                              hipStream_t stream) {
    const float* input_feat = (const float*)d_in[0];
    const float* inter      = (const float*)d_in[1];
    const float* offset_w   = (const float*)d_in[2];
    const float* offset_b   = (const float*)d_in[3];
    const float* weight     = (const float*)d_in[4];
    const float* bias       = (const float*)d_in[5];
    float* out = (float*)d_out;

    float* om     = (float*)d_ws;                 // 1,769,472 f
    float* featT  = om + 1769472;                 // 8,388,608 f
    float* woff_t = featT + 8388608;              //    73,728 f
    float* w_t2   = woff_t + 73728;               //   147,456 f

    transpose_feat<<<8192, 256, 0, stream>>>(input_feat, featT);
    prep_weights<<<864, 256, 0, stream>>>(weight, offset_w, w_t2, woff_t);
    offset_conv<<<512, 256, 0, stream>>>(input_feat, inter, woff_t, offset_b, om);
    dcn_main_f32<<<1024, 256, 0, stream>>>(featT, om, w_t2, bias, out);
}